// Round 6
// baseline (235.941 us; speedup 1.0000x reference)
//
#include <hip/hip_runtime.h>

#pragma clang fp contract(off)

#define NB 32
#define NP 2048
#define NT 128
#define BIGF 1e30f

// Exact replication of the reference cost formula (float32, no FMA contraction).
__device__ __forceinline__ float box_cost(float ox0, float oy0, float ox1, float oy1,
                                          float tx0, float ty0, float tx1, float ty1,
                                          float area1, float area2) {
    float l1 = ((fabsf(ox0 - tx0) + fabsf(oy0 - ty0)) + fabsf(ox1 - tx1)) + fabsf(oy1 - ty1);
    float ltx = fmaxf(ox0, tx0), lty = fmaxf(oy0, ty0);
    float rbx = fminf(ox1, tx1), rby = fminf(oy1, ty1);
    float wx = fmaxf(rbx - ltx, 0.0f), wy = fmaxf(rby - lty, 0.0f);
    float inter = wx * wy;
    float uni = (area1 + area2) - inter;
    float iou = inter / (uni + 1e-8f);
    float ex = fmaxf(fmaxf(ox1, tx1) - fminf(ox0, tx0), 0.0f);
    float ey = fmaxf(fmaxf(oy1, ty1) - fminf(oy0, ty0), 0.0f);
    float earea = ex * ey;
    float giou = iou - (earea - uni) / (earea + 1e-8f);
    return l1 - giou;
}

// Phase 1: cost_T[b][t][p] (rows = targets, cols = preds), [NB][NT][NP] f32.
__global__ __launch_bounds__(256) void cost_kernel(const float* __restrict__ ob,
                                                   const float* __restrict__ tb,
                                                   float* __restrict__ cost) {
    int idx = blockIdx.x * 256 + threadIdx.x;
    int b = idx >> 18;
    int t = (idx >> 11) & (NT - 1);
    int p = idx & (NP - 1);
    float4 o = ((const float4*)ob)[b * NP + p];
    float4 g = ((const float4*)tb)[b * NT + t];
    float a1 = (o.z - o.x) * (o.w - o.y);
    float a2 = (g.z - g.x) * (g.w - g.y);
    cost[idx] = box_cost(o.x, o.y, o.z, o.w, g.x, g.y, g.z, g.w, a1, a2);
}

// ---- DPP wave-wide (val, idx) argmin, first-index tie-break ----
#define DPP_ROW_SHR(n) (0x110 | (n))
#define DPP_BCAST15 0x142
#define DPP_BCAST31 0x143

template <int CTRL>
__device__ __forceinline__ void red_step(float& bv, int& bj) {
    int svi = __builtin_amdgcn_update_dpp(0x7149F2CA /* bits of 1e30f */, __float_as_int(bv),
                                          CTRL, 0xF, 0xF, false);
    int sj = __builtin_amdgcn_update_dpp(NP, bj, CTRL, 0xF, 0xF, false);
    float sv = __int_as_float(svi);
    bool take = (sv < bv) || (sv == bv && sj < bj);
    bv = take ? sv : bv;
    bj = take ? sj : bj;
}

__device__ __forceinline__ void wave_argmin(float& bv, int& bj) {
    red_step<DPP_ROW_SHR(1)>(bv, bj);
    red_step<DPP_ROW_SHR(2)>(bv, bj);
    red_step<DPP_ROW_SHR(4)>(bv, bj);
    red_step<DPP_ROW_SHR(8)>(bv, bj);
    red_step<DPP_BCAST15>(bv, bj);
    red_step<DPP_BCAST31>(bv, bj);
    bv = __int_as_float(__builtin_amdgcn_readlane(__float_as_int(bv), 63));
    bj = __builtin_amdgcn_readlane(bj, 63);
}

#define VC(s) case s: if (lane == ow0) v_r[s] = (v_r[s] + spc_r[s]) - minv; break;

// Read packed row4col byte-reg rr from lane `owner` into dstv (uniform flow).
#define RC_READ(rr, owner, dstv)                                               \
    switch (rr) {                                                              \
        case 0: dstv = (unsigned)__builtin_amdgcn_readlane((int)rc0, owner); break; \
        case 1: dstv = (unsigned)__builtin_amdgcn_readlane((int)rc1, owner); break; \
        case 2: dstv = (unsigned)__builtin_amdgcn_readlane((int)rc2, owner); break; \
        case 3: dstv = (unsigned)__builtin_amdgcn_readlane((int)rc3, owner); break; \
        case 4: dstv = (unsigned)__builtin_amdgcn_readlane((int)rc4, owner); break; \
        case 5: dstv = (unsigned)__builtin_amdgcn_readlane((int)rc5, owner); break; \
        case 6: dstv = (unsigned)__builtin_amdgcn_readlane((int)rc6, owner); break; \
        case 7: dstv = (unsigned)__builtin_amdgcn_readlane((int)rc7, owner); break; \
    }

// On lane `owner`, set byte at shift sh of packed reg rr to val.
#define RC_WRITEBYTE(rr, owner, sh, val)                                       \
    {                                                                          \
        unsigned _m = ~(0xFFu << (sh));                                        \
        unsigned _nb = ((unsigned)(val)) << (sh);                              \
        bool _p = (lane == (owner));                                           \
        switch (rr) {                                                          \
            case 0: rc0 = _p ? ((rc0 & _m) | _nb) : rc0; break;                \
            case 1: rc1 = _p ? ((rc1 & _m) | _nb) : rc1; break;                \
            case 2: rc2 = _p ? ((rc2 & _m) | _nb) : rc2; break;                \
            case 3: rc3 = _p ? ((rc3 & _m) | _nb) : rc3; break;                \
            case 4: rc4 = _p ? ((rc4 & _m) | _nb) : rc4; break;                \
            case 5: rc5 = _p ? ((rc5 & _m) | _nb) : rc5; break;                \
            case 6: rc6 = _p ? ((rc6 & _m) | _nb) : rc6; break;                \
            case 7: rc7 = _p ? ((rc7 & _m) | _nb) : rc7; break;                \
        }                                                                      \
    }

// Row body: consumes CUR (row I's costs), then reissues CUR as prefetch of row I+2.
#define ROW_BODY(I, CUR)                                                               \
  {                                                                                    \
    const int i = (I);                                                                 \
    unsigned SCm = 0, pathm = 0;                                                       \
    int sr01 = 0;                                                                      \
    /* ---- fast first pop: cur=i, minv=0, u[i]=0 -> red = cost - v exactly ---- */    \
    float bv; int bj;                                                                  \
    {                                                                                  \
        float g0v, g2v, g4v, g6v; int g0j, g2j, g4j, g6j;                              \
        _Pragma("unroll") for (int g = 0; g < 8; g += 2) {                             \
            const int sA = g * 4, sB = sA + 4;                                         \
            const int jA = (g << 8) | lane4, jB = ((g + 1) << 8) | lane4;              \
            float a0 = CUR[sA + 0] - v_r[sA + 0]; spc_r[sA + 0] = a0;                  \
            float a1 = CUR[sA + 1] - v_r[sA + 1]; spc_r[sA + 1] = a1;                  \
            float a2 = CUR[sA + 2] - v_r[sA + 2]; spc_r[sA + 2] = a2;                  \
            float a3 = CUR[sA + 3] - v_r[sA + 3]; spc_r[sA + 3] = a3;                  \
            float b0 = CUR[sB + 0] - v_r[sB + 0]; spc_r[sB + 0] = b0;                  \
            float b1 = CUR[sB + 1] - v_r[sB + 1]; spc_r[sB + 1] = b1;                  \
            float b2 = CUR[sB + 2] - v_r[sB + 2]; spc_r[sB + 2] = b2;                  \
            float b3 = CUR[sB + 3] - v_r[sB + 3]; spc_r[sB + 3] = b3;                  \
            float mA = a0; int qA = jA;                                                \
            if (a1 < mA) { mA = a1; qA = jA + 1; }                                     \
            float mC = a2; int qC = jA + 2;                                            \
            if (a3 < mC) { mC = a3; qC = jA + 3; }                                     \
            if (mC < mA) { mA = mC; qA = qC; }                                         \
            float mB = b0; int qB = jB;                                                \
            if (b1 < mB) { mB = b1; qB = jB + 1; }                                     \
            float mD = b2; int qD = jB + 2;                                            \
            if (b3 < mD) { mD = b3; qD = jB + 3; }                                     \
            if (mD < mB) { mB = mD; qB = qD; }                                         \
            if (mB < mA) { mA = mB; qA = qB; }                                         \
            if (g == 0) { g0v = mA; g0j = qA; }                                        \
            else if (g == 2) { g2v = mA; g2j = qA; }                                   \
            else if (g == 4) { g4v = mA; g4j = qA; }                                   \
            else { g6v = mA; g6j = qA; }                                               \
        }                                                                              \
        if (g2v < g0v) { g0v = g2v; g0j = g2j; }                                       \
        if (g6v < g4v) { g4v = g6v; g4j = g6j; }                                       \
        if (g4v < g0v) { g0v = g4v; g0j = g4j; }                                       \
        bv = g0v; bj = g0j;                                                            \
    }                                                                                  \
    /* reissue CUR as prefetch of row i+2 (regs dead after the subs above) */          \
    if (i + 2 < NT) {                                                                  \
        const float4* nrow = (const float4*)(costb + (size_t)(i + 2) * NP);            \
        _Pragma("unroll") for (int g = 0; g < 8; ++g) {                                \
            float4 t4 = nrow[g * 64 + lane];                                           \
            CUR[g * 4 + 0] = t4.x; CUR[g * 4 + 1] = t4.y;                              \
            CUR[g * 4 + 2] = t4.z; CUR[g * 4 + 3] = t4.w;                              \
        }                                                                              \
    }                                                                                  \
    wave_argmin(bv, bj);                                                               \
    float mv = bv; int mj = bj;                                                        \
    int ow0 = (mj >> 2) & 63, sl0 = ((mj >> 8) << 2) | (mj & 3);                       \
    if (lane == ow0) SCm |= (1u << sl0);                                               \
    int r0 = sl0 >> 2, sh0 = (sl0 & 3) << 3;                                           \
    unsigned pk = 0;                                                                   \
    RC_READ(r0, ow0, pk);                                                              \
    int rowp = (int)((pk >> sh0) & 0xFFu);                                             \
    if (rowp == 0) {                                                                   \
        /* ---- npops==1 epilogue: SC={sink}, path[sink]=i implicit ---- */            \
        const float minv = mv; const int sink = mj;                                    \
        if ((i & 63) == lane) { if (i < 64) u0 = u0 + minv; else u1 = u1 + minv; }     \
        switch (sl0) {                                                                 \
            VC(0) VC(1) VC(2) VC(3) VC(4) VC(5) VC(6) VC(7)                            \
            VC(8) VC(9) VC(10) VC(11) VC(12) VC(13) VC(14) VC(15)                      \
            VC(16) VC(17) VC(18) VC(19) VC(20) VC(21) VC(22) VC(23)                    \
            VC(24) VC(25) VC(26) VC(27) VC(28) VC(29) VC(30) VC(31)                    \
        }                                                                              \
        RC_WRITEBYTE(r0, ow0, sh0, i + 1);                                             \
        if (i < 64) c4r0 = (lane == i) ? sink : c4r0;                                  \
        else        c4r1 = (lane == (i - 64)) ? sink : c4r1;                           \
    } else {                                                                           \
        /* ---- general shortest-path continuation ---- */                             \
        int r = rowp - 1;                                                              \
        do {                                                                           \
            if ((r & 63) == lane) {                                                    \
                if (r < 64) { sr01 |= 1; pm0 = mv; }                                   \
                else        { sr01 |= 2; pm1 = mv; }                                   \
            }                                                                          \
            const int cur = r;                                                         \
            float usel = (cur >= 64) ? u1 : u0;                                        \
            float ucur = __int_as_float(                                               \
                __builtin_amdgcn_readlane(__float_as_int(usel), cur & 63));            \
            const float4* rrow = (const float4*)(costb + (size_t)cur * NP);            \
            _Pragma("unroll") for (int g = 0; g < 8; ++g) {                            \
                float4 t4 = rrow[g * 64 + lane];                                       \
                cr[g * 4 + 0] = t4.x; cr[g * 4 + 1] = t4.y;                            \
                cr[g * 4 + 2] = t4.z; cr[g * 4 + 3] = t4.w;                            \
            }                                                                          \
            bv = BIGF; bj = NP;                                                        \
            _Pragma("unroll") for (int s = 0; s < 32; ++s) {                           \
                float red = ((mv + cr[s]) - ucur) - v_r[s];                            \
                bool notSC = ((SCm >> s) & 1u) == 0u;                                  \
                bool imp = notSC && (red < spc_r[s]);                                  \
                spc_r[s] = imp ? red : spc_r[s];                                       \
                path_r[s] = imp ? cur : path_r[s];                                     \
                pathm = imp ? (pathm | (1u << s)) : pathm;                             \
                float cand = notSC ? spc_r[s] : BIGF;                                  \
                int j = (((s >> 2) << 8) | (s & 3)) | lane4;                           \
                if (cand < bv) { bv = cand; bj = j; }                                  \
            }                                                                          \
            wave_argmin(bv, bj);                                                       \
            mv = bv; mj = bj;                                                          \
            ow0 = (mj >> 2) & 63; sl0 = ((mj >> 8) << 2) | (mj & 3);                   \
            if (lane == ow0) SCm |= (1u << sl0);                                       \
            r0 = sl0 >> 2; sh0 = (sl0 & 3) << 3;                                       \
            RC_READ(r0, ow0, pk);                                                      \
            rowp = (int)((pk >> sh0) & 0xFFu);                                         \
            r = rowp - 1;                                                              \
        } while (rowp != 0);                                                           \
        const int sink = mj; const float minv = mv;                                    \
        if ((i & 63) == lane) { if (i < 64) u0 = u0 + minv; else u1 = u1 + minv; }     \
        if (sr01 & 1) u0 = (u0 + minv) - pm0;                                          \
        if (sr01 & 2) u1 = (u1 + minv) - pm1;                                          \
        _Pragma("unroll") for (int s = 0; s < 32; ++s) {                               \
            if ((SCm >> s) & 1u) v_r[s] = (v_r[s] + spc_r[s]) - minv;                  \
        }                                                                              \
        /* augment along alternating path */                                           \
        int j = sink;                                                                  \
        while (true) {                                                                 \
            int sl = ((j >> 8) << 2) | (j & 3);                                        \
            int ow = (j >> 2) & 63;                                                    \
            int pv = ((pathm >> 0) & 1u) ? path_r[0] : i;                              \
            _Pragma("unroll") for (int s = 1; s < 32; ++s) {                           \
                int leaf = ((pathm >> s) & 1u) ? path_r[s] : i;                        \
                pv = (sl == s) ? leaf : pv;                                            \
            }                                                                          \
            int ii = __builtin_amdgcn_readlane(pv, ow);                                \
            { int rrW = sl >> 2, shW = (sl & 3) << 3;                                  \
              RC_WRITEBYTE(rrW, ow, shW, ii + 1); }                                    \
            int nj;                                                                    \
            if (ii < 64) nj = __builtin_amdgcn_readlane(c4r0, ii);                     \
            else         nj = __builtin_amdgcn_readlane(c4r1, ii - 64);                \
            if (ii < 64) c4r0 = (lane == ii) ? j : c4r0;                               \
            else         c4r1 = (lane == (ii - 64)) ? j : c4r1;                        \
            if (ii == i) break;                                                        \
            j = nj;                                                                    \
        }                                                                              \
    }                                                                                  \
  }

// Phase 2: wave-synchronous JV LSAP. One 64-lane wave per batch.
// Column j: owner lane = (j>>2)&63, slot = ((j>>8)<<2)|(j&3).
// row4col packed as bytes (row+1, 0=unassigned) in rc0..rc7 on the owner lane.
// col4row: lane L holds rows L (c4r0) and L+64 (c4r1).
__global__ __launch_bounds__(64) void solve_wave(const float* __restrict__ cost,
                                                 int* __restrict__ out) {
    __shared__ int col4row_lds[NT];

    const int lane = threadIdx.x;
    const int lane4 = lane << 2;
    const int b = blockIdx.x;
    const float* costb = cost + (size_t)b * NT * NP;

    float pfA[32], pfB[32], v_r[32], spc_r[32], cr[32];
    int path_r[32];
    unsigned rc0 = 0, rc1 = 0, rc2 = 0, rc3 = 0, rc4 = 0, rc5 = 0, rc6 = 0, rc7 = 0;
    int c4r0 = -1, c4r1 = -1;
    float u0 = 0.0f, u1 = 0.0f, pm0 = 0.0f, pm1 = 0.0f;

#pragma unroll
    for (int s = 0; s < 32; ++s) { v_r[s] = 0.0f; path_r[s] = 0; }

    {   // prologue: load row 0 -> pfA, row 1 -> pfB
        const float4* r0 = (const float4*)costb;
        const float4* r1 = (const float4*)(costb + NP);
#pragma unroll
        for (int g = 0; g < 8; ++g) {
            float4 t4 = r0[g * 64 + lane];
            pfA[g * 4 + 0] = t4.x; pfA[g * 4 + 1] = t4.y;
            pfA[g * 4 + 2] = t4.z; pfA[g * 4 + 3] = t4.w;
        }
#pragma unroll
        for (int g = 0; g < 8; ++g) {
            float4 t4 = r1[g * 64 + lane];
            pfB[g * 4 + 0] = t4.x; pfB[g * 4 + 1] = t4.y;
            pfB[g * 4 + 2] = t4.z; pfB[g * 4 + 3] = t4.w;
        }
    }

    for (int ih = 0; ih < NT / 2; ++ih) {
        ROW_BODY(2 * ih, pfA)
        ROW_BODY(2 * ih + 1, pfB)
    }

    // output: sort targets by assigned pred index (all distinct)
    col4row_lds[lane] = c4r0;
    col4row_lds[lane + 64] = c4r1;
    for (int t = lane; t < NT; t += 64) {
        int c = col4row_lds[t];
        int rank = 0;
        for (int t2 = 0; t2 < NT; ++t2) rank += (col4row_lds[t2] < c) ? 1 : 0;
        out[(b * 2 + 0) * NT + rank] = c;
        out[(b * 2 + 1) * NT + rank] = t;
    }
}

// Fallback (ws too small): LDS-based block solver computing costs on the fly.
__global__ __launch_bounds__(512) void solve_fallback(const float* __restrict__ ob,
                                                      const float* __restrict__ tb,
                                                      int* __restrict__ out) {
    __shared__ float v[NP], spc[NP];
    __shared__ int path[NP], row4col[NP];
    __shared__ unsigned char SC[NP];
    __shared__ float u[NT];
    __shared__ int col4row[NT];
    __shared__ unsigned char SR[NT];
    __shared__ float rv[8];
    __shared__ int ri[8];
    __shared__ int s_cur, s_sink;
    __shared__ float s_minv;
    __shared__ float px0[NP], py0[NP], px1[NP], py1[NP], pa[NP];
    __shared__ float tx0[NT], ty0[NT], tx1[NT], ty1[NT], ta[NT];

    const int tid = threadIdx.x;
    const int b = blockIdx.x;

    for (int j = tid; j < NP; j += 512) {
        v[j] = 0.0f; row4col[j] = -1;
        float4 o = ((const float4*)ob)[b * NP + j];
        px0[j] = o.x; py0[j] = o.y; px1[j] = o.z; py1[j] = o.w;
        pa[j] = (o.z - o.x) * (o.w - o.y);
    }
    for (int t = tid; t < NT; t += 512) {
        u[t] = 0.0f; col4row[t] = -1;
        float4 g = ((const float4*)tb)[b * NT + t];
        tx0[t] = g.x; ty0[t] = g.y; tx1[t] = g.z; ty1[t] = g.w;
        ta[t] = (g.z - g.x) * (g.w - g.y);
    }
    __syncthreads();

    for (int i = 0; i < NT; ++i) {
        for (int j = tid; j < NP; j += 512) { spc[j] = BIGF; SC[j] = 0; }
        for (int t = tid; t < NT; t += 512) SR[t] = 0;
        if (tid == 0) { s_cur = i; s_minv = 0.0f; s_sink = -1; }
        __syncthreads();

        while (s_sink < 0) {
            const int cur = s_cur;
            const float minv = s_minv;
            if (tid == 0) SR[cur] = 1;
            const float ucur = u[cur];
            float c0 = tx0[cur], c1 = ty0[cur], c2 = tx1[cur], c3 = ty1[cur], ca = ta[cur];
            float bv = BIGF;
            int bi = NP;
            for (int k = 0; k < NP / 512; ++k) {
                int j = tid + k * 512;
                float cj = box_cost(px0[j], py0[j], px1[j], py1[j], c0, c1, c2, c3, pa[j], ca);
                float cand;
                if (!SC[j]) {
                    float red = ((minv + cj) - ucur) - v[j];
                    if (red < spc[j]) { spc[j] = red; path[j] = cur; }
                    cand = spc[j];
                } else {
                    cand = BIGF;
                }
                if (cand < bv || (cand == bv && j < bi)) { bv = cand; bi = j; }
            }
            for (int off = 32; off >= 1; off >>= 1) {
                float ov = __shfl_xor(bv, off);
                int oi = __shfl_xor(bi, off);
                if (ov < bv || (ov == bv && oi < bi)) { bv = ov; bi = oi; }
            }
            if ((tid & 63) == 0) { rv[tid >> 6] = bv; ri[tid >> 6] = bi; }
            __syncthreads();
            if (tid == 0) {
                float mvv = rv[0]; int mjj = ri[0];
                for (int w = 1; w < 8; ++w)
                    if (rv[w] < mvv || (rv[w] == mvv && ri[w] < mjj)) { mvv = rv[w]; mjj = ri[w]; }
                s_minv = mvv;
                SC[mjj] = 1;
                int rr = row4col[mjj];
                if (rr < 0) s_sink = mjj; else s_cur = rr;
            }
            __syncthreads();
        }

        const float minv = s_minv;
        const int sink = s_sink;
        for (int j = tid; j < NP; j += 512) if (SC[j]) v[j] = (v[j] + spc[j]) - minv;
        for (int t = tid; t < NT; t += 512) {
            if (t == i) u[t] = u[t] + minv;
            else if (SR[t]) u[t] = (u[t] + minv) - spc[col4row[t]];
        }
        __syncthreads();
        if (tid == 0) {
            int j = sink;
            while (true) {
                int ii = path[j];
                row4col[j] = ii;
                int nj = col4row[ii];
                col4row[ii] = j;
                if (ii == i) break;
                j = nj;
            }
        }
        __syncthreads();
    }

    if (tid < NT) {
        int c = col4row[tid];
        int rank = 0;
        for (int t2 = 0; t2 < NT; ++t2) rank += (col4row[t2] < c) ? 1 : 0;
        out[(b * 2 + 0) * NT + rank] = c;
        out[(b * 2 + 1) * NT + rank] = tid;
    }
}

extern "C" void kernel_launch(void* const* d_in, const int* in_sizes, int n_in,
                              void* d_out, int out_size, void* d_ws, size_t ws_size,
                              hipStream_t stream) {
    const float* ob = (const float*)d_in[0];   // [32, 2048, 4] f32
    const float* tb = (const float*)d_in[1];   // [32, 128, 4] f32
    int* out = (int*)d_out;                    // [32, 2, 128] int32

    const size_t need = (size_t)NB * NT * NP * sizeof(float);  // 32 MB
    if (ws_size >= need) {
        float* cost = (float*)d_ws;
        cost_kernel<<<(NB * NT * NP) / 256, 256, 0, stream>>>(ob, tb, cost);
        solve_wave<<<NB, 64, 0, stream>>>(cost, out);
    } else {
        solve_fallback<<<NB, 512, 0, stream>>>(ob, tb, out);
    }
}

// Round 8
// 200.648 us; speedup vs baseline: 1.1759x; 1.1759x over previous
//
#include <hip/hip_runtime.h>

#pragma clang fp contract(off)

#define NB 32
#define NP 2048
#define NT 128
#define BIGF 1e30f

// Exact replication of the reference cost formula (float32, no FMA contraction).
__device__ __forceinline__ float box_cost(float ox0, float oy0, float ox1, float oy1,
                                          float tx0, float ty0, float tx1, float ty1,
                                          float area1, float area2) {
    float l1 = ((fabsf(ox0 - tx0) + fabsf(oy0 - ty0)) + fabsf(ox1 - tx1)) + fabsf(oy1 - ty1);
    float ltx = fmaxf(ox0, tx0), lty = fmaxf(oy0, ty0);
    float rbx = fminf(ox1, tx1), rby = fminf(oy1, ty1);
    float wx = fmaxf(rbx - ltx, 0.0f), wy = fmaxf(rby - lty, 0.0f);
    float inter = wx * wy;
    float uni = (area1 + area2) - inter;
    float iou = inter / (uni + 1e-8f);
    float ex = fmaxf(fmaxf(ox1, tx1) - fminf(ox0, tx0), 0.0f);
    float ey = fmaxf(fmaxf(oy1, ty1) - fminf(oy0, ty0), 0.0f);
    float earea = ex * ey;
    float giou = iou - (earea - uni) / (earea + 1e-8f);
    return l1 - giou;
}

// Phase 1: cost_T[b][t][p] (rows = targets, cols = preds), [NB][NT][NP] f32.
// XCD-aware block remap: gfx950 round-robins blockIdx over 8 XCDs (block m ->
// XCD m%8). Map so ALL blocks writing batch b run on XCD b%8; solve_wave's
// natural mapping (block b -> XCD b%8) then reads batch b from the same L2.
// 4 batches/XCD x 1MB = 4MB = one XCD's L2.
__global__ __launch_bounds__(256) void cost_kernel(const float* __restrict__ ob,
                                                   const float* __restrict__ tb,
                                                   float* __restrict__ cost) {
    int m = blockIdx.x;
    int x = m & 7;                 // XCD
    int q = m >> 3;                // 0..4095
    int b = x + 8 * (q >> 10);     // batch with b%8 == x
    int inner = q & 1023;          // 1024 blocks per batch
    int ofs = inner * 256 + (int)threadIdx.x;  // 0..NT*NP-1
    int t = ofs >> 11;
    int p = ofs & (NP - 1);
    float4 o = ((const float4*)ob)[b * NP + p];
    float4 g = ((const float4*)tb)[b * NT + t];
    float a1 = (o.z - o.x) * (o.w - o.y);
    float a2 = (g.z - g.x) * (g.w - g.y);
    cost[(size_t)b * NT * NP + ofs] = box_cost(o.x, o.y, o.z, o.w, g.x, g.y, g.z, g.w, a1, a2);
}

// ---- DPP wave-wide (val, idx) argmin, first-index tie-break ----
#define DPP_ROW_SHR(n) (0x110 | (n))
#define DPP_BCAST15 0x142
#define DPP_BCAST31 0x143

template <int CTRL>
__device__ __forceinline__ void red_step(float& bv, int& bj) {
    int svi = __builtin_amdgcn_update_dpp(0x7149F2CA /* bits of 1e30f */, __float_as_int(bv),
                                          CTRL, 0xF, 0xF, false);
    int sj = __builtin_amdgcn_update_dpp(NP, bj, CTRL, 0xF, 0xF, false);
    float sv = __int_as_float(svi);
    bool take = (sv < bv) || (sv == bv && sj < bj);
    bv = take ? sv : bv;
    bj = take ? sj : bj;
}

__device__ __forceinline__ void wave_argmin(float& bv, int& bj) {
    red_step<DPP_ROW_SHR(1)>(bv, bj);
    red_step<DPP_ROW_SHR(2)>(bv, bj);
    red_step<DPP_ROW_SHR(4)>(bv, bj);
    red_step<DPP_ROW_SHR(8)>(bv, bj);
    red_step<DPP_BCAST15>(bv, bj);
    red_step<DPP_BCAST31>(bv, bj);
    bv = __int_as_float(__builtin_amdgcn_readlane(__float_as_int(bv), 63));
    bj = __builtin_amdgcn_readlane(bj, 63);
}

#define VC(s) case s: if (lane == ow0) v_r[s] = (v_r[s] + spc_r[s]) - minv; break;

// Row body: consumes CUR (row I's costs), prefetches row I+1 into NXT at start.
#define ROW_BODY(I, CUR, NXT)                                                          \
  {                                                                                    \
    const int i = (I);                                                                 \
    if (i + 1 < NT) {                                                                  \
        const float4* nrow = (const float4*)(costb + (size_t)(i + 1) * NP);            \
        _Pragma("unroll") for (int g = 0; g < 8; ++g) {                                \
            float4 t4 = nrow[g * 64 + lane];                                           \
            NXT[g * 4 + 0] = t4.x; NXT[g * 4 + 1] = t4.y;                              \
            NXT[g * 4 + 2] = t4.z; NXT[g * 4 + 3] = t4.w;                              \
        }                                                                              \
    }                                                                                  \
    unsigned SCm = 0, pathm = 0;                                                       \
    int sr01 = 0;                                                                      \
    /* ---- fast first pop: cur=i, minv=0, u[i]=0 -> red = cost - v exactly ---- */    \
    float bv; int bj;                                                                  \
    {                                                                                  \
        float g0v, g2v, g4v, g6v; int g0j, g2j, g4j, g6j;                              \
        _Pragma("unroll") for (int g = 0; g < 8; g += 2) {                             \
            const int sA = g * 4, sB = sA + 4;                                         \
            const int jA = (g << 8) | lane4, jB = ((g + 1) << 8) | lane4;              \
            float a0 = CUR[sA + 0] - v_r[sA + 0]; spc_r[sA + 0] = a0;                  \
            float a1 = CUR[sA + 1] - v_r[sA + 1]; spc_r[sA + 1] = a1;                  \
            float a2 = CUR[sA + 2] - v_r[sA + 2]; spc_r[sA + 2] = a2;                  \
            float a3 = CUR[sA + 3] - v_r[sA + 3]; spc_r[sA + 3] = a3;                  \
            float b0 = CUR[sB + 0] - v_r[sB + 0]; spc_r[sB + 0] = b0;                  \
            float b1 = CUR[sB + 1] - v_r[sB + 1]; spc_r[sB + 1] = b1;                  \
            float b2 = CUR[sB + 2] - v_r[sB + 2]; spc_r[sB + 2] = b2;                  \
            float b3 = CUR[sB + 3] - v_r[sB + 3]; spc_r[sB + 3] = b3;                  \
            float mA = a0; int qA = jA;                                                \
            if (a1 < mA) { mA = a1; qA = jA + 1; }                                     \
            float mC = a2; int qC = jA + 2;                                            \
            if (a3 < mC) { mC = a3; qC = jA + 3; }                                     \
            if (mC < mA) { mA = mC; qA = qC; }                                         \
            float mB = b0; int qB = jB;                                                \
            if (b1 < mB) { mB = b1; qB = jB + 1; }                                     \
            float mD = b2; int qD = jB + 2;                                            \
            if (b3 < mD) { mD = b3; qD = jB + 3; }                                     \
            if (mD < mB) { mB = mD; qB = qD; }                                         \
            if (mB < mA) { mA = mB; qA = qB; }                                         \
            if (g == 0) { g0v = mA; g0j = qA; }                                        \
            else if (g == 2) { g2v = mA; g2j = qA; }                                   \
            else if (g == 4) { g4v = mA; g4j = qA; }                                   \
            else { g6v = mA; g6j = qA; }                                               \
        }                                                                              \
        if (g2v < g0v) { g0v = g2v; g0j = g2j; }                                       \
        if (g6v < g4v) { g4v = g6v; g4j = g6j; }                                       \
        if (g4v < g0v) { g0v = g4v; g0j = g4j; }                                       \
        bv = g0v; bj = g0j;                                                            \
    }                                                                                  \
    wave_argmin(bv, bj);                                                               \
    float mv = bv; int mj = bj;                                                        \
    if (((mj >> 2) & 63) == lane) SCm |= (1u << (((mj >> 8) << 2) | (mj & 3)));        \
    int npops = 1;                                                                     \
    int r = row4col[mj];                                                               \
    if (r >= 0) {                                                                      \
        /* ---- general shortest-path continuation ---- */                             \
        do {                                                                           \
            if ((r & 63) == lane) {                                                    \
                if (r < 64) { sr01 |= 1; pm0 = mv; }                                   \
                else        { sr01 |= 2; pm1 = mv; }                                   \
            }                                                                          \
            const int cur = r;                                                         \
            float usel = (cur >= 64) ? u1 : u0;                                        \
            float ucur = __int_as_float(                                               \
                __builtin_amdgcn_readlane(__float_as_int(usel), cur & 63));            \
            const float4* rrow = (const float4*)(costb + (size_t)cur * NP);            \
            _Pragma("unroll") for (int g = 0; g < 8; ++g) {                            \
                float4 t4 = rrow[g * 64 + lane];                                       \
                cr[g * 4 + 0] = t4.x; cr[g * 4 + 1] = t4.y;                            \
                cr[g * 4 + 2] = t4.z; cr[g * 4 + 3] = t4.w;                            \
            }                                                                          \
            bv = BIGF; bj = NP;                                                        \
            _Pragma("unroll") for (int s = 0; s < 32; ++s) {                           \
                float red = ((mv + cr[s]) - ucur) - v_r[s];                            \
                bool notSC = ((SCm >> s) & 1u) == 0u;                                  \
                bool imp = notSC && (red < spc_r[s]);                                  \
                spc_r[s] = imp ? red : spc_r[s];                                       \
                path_r[s] = imp ? cur : path_r[s];                                     \
                pathm = imp ? (pathm | (1u << s)) : pathm;                             \
                float cand = notSC ? spc_r[s] : BIGF;                                  \
                int j = (((s >> 2) << 8) | (s & 3)) | lane4;                           \
                if (cand < bv) { bv = cand; bj = j; }                                  \
            }                                                                          \
            wave_argmin(bv, bj);                                                       \
            mv = bv; mj = bj;                                                          \
            if (((mj >> 2) & 63) == lane) SCm |= (1u << (((mj >> 8) << 2) | (mj & 3))); \
            ++npops;                                                                   \
            r = row4col[mj];                                                           \
        } while (r >= 0);                                                              \
    }                                                                                  \
    const int sink = mj;                                                               \
    const float minv = mv;                                                             \
    /* ---- dual updates (exact reference order) ---- */                               \
    if ((i & 63) == lane) { if (i < 64) u0 = u0 + minv; else u1 = u1 + minv; }         \
    if (sr01 & 1) u0 = (u0 + minv) - pm0;                                              \
    if (sr01 & 2) u1 = (u1 + minv) - pm1;                                              \
    if (npops == 1) {                                                                  \
        /* SC = {sink}: single-slot v-update, uniform scalar switch */                 \
        const int ow0 = (sink >> 2) & 63;                                              \
        switch (((sink >> 8) << 2) | (sink & 3)) {                                     \
            VC(0) VC(1) VC(2) VC(3) VC(4) VC(5) VC(6) VC(7)                            \
            VC(8) VC(9) VC(10) VC(11) VC(12) VC(13) VC(14) VC(15)                      \
            VC(16) VC(17) VC(18) VC(19) VC(20) VC(21) VC(22) VC(23)                    \
            VC(24) VC(25) VC(26) VC(27) VC(28) VC(29) VC(30) VC(31)                    \
        }                                                                              \
        if (lane == 0) { row4col[sink] = i; col4row[i] = sink; }                       \
    } else {                                                                           \
        _Pragma("unroll") for (int s = 0; s < 32; ++s) {                               \
            if ((SCm >> s) & 1u) v_r[s] = (v_r[s] + spc_r[s]) - minv;                  \
        }                                                                              \
        int j = sink;                                                                  \
        while (true) {                                                                 \
            int sl = ((j >> 8) << 2) | (j & 3);                                        \
            int ow = (j >> 2) & 63;                                                    \
            int pv = ((pathm >> 0) & 1u) ? path_r[0] : i;                              \
            _Pragma("unroll") for (int s = 1; s < 32; ++s) {                           \
                int leaf = ((pathm >> s) & 1u) ? path_r[s] : i;                        \
                pv = (sl == s) ? leaf : pv;                                            \
            }                                                                          \
            int ii = __shfl(pv, ow);                                                   \
            if (lane == 0) row4col[j] = ii;                                            \
            int nj = col4row[ii];                                                      \
            if (lane == 0) col4row[ii] = j;                                            \
            if (ii == i) break;                                                        \
            j = nj;                                                                    \
        }                                                                              \
    }                                                                                  \
  }

// Phase 2: wave-synchronous JV LSAP. One 64-lane wave per batch.
// Column j: owner lane = (j>>2)&63, slot = ((j>>8)<<2)|(j&3).
__global__ __launch_bounds__(64) void solve_wave(const float* __restrict__ cost,
                                                 int* __restrict__ out) {
    __shared__ int row4col[NP];
    __shared__ int col4row[NT];

    const int lane = threadIdx.x;
    const int lane4 = lane << 2;
    const int b = blockIdx.x;
    const float* costb = cost + (size_t)b * NT * NP;

    float pfA[32], pfB[32], v_r[32], spc_r[32], cr[32];
    int path_r[32];
    float u0 = 0.0f, u1 = 0.0f, pm0 = 0.0f, pm1 = 0.0f;

#pragma unroll
    for (int s = 0; s < 32; ++s) { v_r[s] = 0.0f; path_r[s] = 0; }
    for (int j = lane; j < NP; j += 64) row4col[j] = -1;
    col4row[lane] = -1;
    col4row[lane + 64] = -1;

    {   // prefetch row 0 into pfA
        const float4* r0 = (const float4*)costb;
#pragma unroll
        for (int g = 0; g < 8; ++g) {
            float4 t4 = r0[g * 64 + lane];
            pfA[g * 4 + 0] = t4.x; pfA[g * 4 + 1] = t4.y;
            pfA[g * 4 + 2] = t4.z; pfA[g * 4 + 3] = t4.w;
        }
    }

    for (int ih = 0; ih < NT / 2; ++ih) {
        ROW_BODY(2 * ih, pfA, pfB)
        ROW_BODY(2 * ih + 1, pfB, pfA)
    }

    // output: sort targets by assigned pred index (all distinct)
    for (int t = lane; t < NT; t += 64) {
        int c = col4row[t];
        int rank = 0;
        for (int t2 = 0; t2 < NT; ++t2) rank += (col4row[t2] < c) ? 1 : 0;
        out[(b * 2 + 0) * NT + rank] = c;
        out[(b * 2 + 1) * NT + rank] = t;
    }
}

// Fallback (ws too small): LDS-based block solver computing costs on the fly.
__global__ __launch_bounds__(512) void solve_fallback(const float* __restrict__ ob,
                                                      const float* __restrict__ tb,
                                                      int* __restrict__ out) {
    __shared__ float v[NP], spc[NP];
    __shared__ int path[NP], row4col[NP];
    __shared__ unsigned char SC[NP];
    __shared__ float u[NT];
    __shared__ int col4row[NT];
    __shared__ unsigned char SR[NT];
    __shared__ float rv[8];
    __shared__ int ri[8];
    __shared__ int s_cur, s_sink;
    __shared__ float s_minv;
    __shared__ float px0[NP], py0[NP], px1[NP], py1[NP], pa[NP];
    __shared__ float tx0[NT], ty0[NT], tx1[NT], ty1[NT], ta[NT];

    const int tid = threadIdx.x;
    const int b = blockIdx.x;

    for (int j = tid; j < NP; j += 512) {
        v[j] = 0.0f; row4col[j] = -1;
        float4 o = ((const float4*)ob)[b * NP + j];
        px0[j] = o.x; py0[j] = o.y; px1[j] = o.z; py1[j] = o.w;
        pa[j] = (o.z - o.x) * (o.w - o.y);
    }
    for (int t = tid; t < NT; t += 512) {
        u[t] = 0.0f; col4row[t] = -1;
        float4 g = ((const float4*)tb)[b * NT + t];
        tx0[t] = g.x; ty0[t] = g.y; tx1[t] = g.z; ty1[t] = g.w;
        ta[t] = (g.z - g.x) * (g.w - g.y);
    }
    __syncthreads();

    for (int i = 0; i < NT; ++i) {
        for (int j = tid; j < NP; j += 512) { spc[j] = BIGF; SC[j] = 0; }
        for (int t = tid; t < NT; t += 512) SR[t] = 0;
        if (tid == 0) { s_cur = i; s_minv = 0.0f; s_sink = -1; }
        __syncthreads();

        while (s_sink < 0) {
            const int cur = s_cur;
            const float minv = s_minv;
            if (tid == 0) SR[cur] = 1;
            const float ucur = u[cur];
            float c0 = tx0[cur], c1 = ty0[cur], c2 = tx1[cur], c3 = ty1[cur], ca = ta[cur];
            float bv = BIGF;
            int bi = NP;
            for (int k = 0; k < NP / 512; ++k) {
                int j = tid + k * 512;
                float cj = box_cost(px0[j], py0[j], px1[j], py1[j], c0, c1, c2, c3, pa[j], ca);
                float cand;
                if (!SC[j]) {
                    float red = ((minv + cj) - ucur) - v[j];
                    if (red < spc[j]) { spc[j] = red; path[j] = cur; }
                    cand = spc[j];
                } else {
                    cand = BIGF;
                }
                if (cand < bv || (cand == bv && j < bi)) { bv = cand; bi = j; }
            }
            for (int off = 32; off >= 1; off >>= 1) {
                float ov = __shfl_xor(bv, off);
                int oi = __shfl_xor(bi, off);
                if (ov < bv || (ov == bv && oi < bi)) { bv = ov; bi = oi; }
            }
            if ((tid & 63) == 0) { rv[tid >> 6] = bv; ri[tid >> 6] = bi; }
            __syncthreads();
            if (tid == 0) {
                float mvv = rv[0]; int mjj = ri[0];
                for (int w = 1; w < 8; ++w)
                    if (rv[w] < mvv || (rv[w] == mvv && ri[w] < mjj)) { mvv = rv[w]; mjj = ri[w]; }
                s_minv = mvv;
                SC[mjj] = 1;
                int rr = row4col[mjj];
                if (rr < 0) s_sink = mjj; else s_cur = rr;
            }
            __syncthreads();
        }

        const float minv = s_minv;
        const int sink = s_sink;
        for (int j = tid; j < NP; j += 512) if (SC[j]) v[j] = (v[j] + spc[j]) - minv;
        for (int t = tid; t < NT; t += 512) {
            if (t == i) u[t] = u[t] + minv;
            else if (SR[t]) u[t] = (u[t] + minv) - spc[col4row[t]];
        }
        __syncthreads();
        if (tid == 0) {
            int j = sink;
            while (true) {
                int ii = path[j];
                row4col[j] = ii;
                int nj = col4row[ii];
                col4row[ii] = j;
                if (ii == i) break;
                j = nj;
            }
        }
        __syncthreads();
    }

    if (tid < NT) {
        int c = col4row[tid];
        int rank = 0;
        for (int t2 = 0; t2 < NT; ++t2) rank += (col4row[t2] < c) ? 1 : 0;
        out[(b * 2 + 0) * NT + rank] = c;
        out[(b * 2 + 1) * NT + rank] = tid;
    }
}

extern "C" void kernel_launch(void* const* d_in, const int* in_sizes, int n_in,
                              void* d_out, int out_size, void* d_ws, size_t ws_size,
                              hipStream_t stream) {
    const float* ob = (const float*)d_in[0];   // [32, 2048, 4] f32
    const float* tb = (const float*)d_in[1];   // [32, 128, 4] f32
    int* out = (int*)d_out;                    // [32, 2, 128] int32

    const size_t need = (size_t)NB * NT * NP * sizeof(float);  // 32 MB
    if (ws_size >= need) {
        float* cost = (float*)d_ws;
        cost_kernel<<<(NB * NT * NP) / 256, 256, 0, stream>>>(ob, tb, cost);
        solve_wave<<<NB, 64, 0, stream>>>(cost, out);
    } else {
        solve_fallback<<<NB, 512, 0, stream>>>(ob, tb, out);
    }
}

// Round 9
// 172.122 us; speedup vs baseline: 1.3708x; 1.1657x over previous
//
#include <hip/hip_runtime.h>

#pragma clang fp contract(off)

#define NB 32
#define NP 2048
#define NT 128
#define BIGF 1e30f

// Exact replication of the reference cost formula (float32, no FMA contraction).
__device__ __forceinline__ float box_cost(float ox0, float oy0, float ox1, float oy1,
                                          float tx0, float ty0, float tx1, float ty1,
                                          float area1, float area2) {
    float l1 = ((fabsf(ox0 - tx0) + fabsf(oy0 - ty0)) + fabsf(ox1 - tx1)) + fabsf(oy1 - ty1);
    float ltx = fmaxf(ox0, tx0), lty = fmaxf(oy0, ty0);
    float rbx = fminf(ox1, tx1), rby = fminf(oy1, ty1);
    float wx = fmaxf(rbx - ltx, 0.0f), wy = fmaxf(rby - lty, 0.0f);
    float inter = wx * wy;
    float uni = (area1 + area2) - inter;
    float iou = inter / (uni + 1e-8f);
    float ex = fmaxf(fmaxf(ox1, tx1) - fminf(ox0, tx0), 0.0f);
    float ey = fmaxf(fmaxf(oy1, ty1) - fminf(oy0, ty0), 0.0f);
    float earea = ex * ey;
    float giou = iou - (earea - uni) / (earea + 1e-8f);
    return l1 - giou;
}

// Phase 1: cost_T[b][t][p] (rows = targets, cols = preds), [NB][NT][NP] f32.
// XCD-aware block remap (kept from R8: helped total by ~14us on the write side).
__global__ __launch_bounds__(256) void cost_kernel(const float* __restrict__ ob,
                                                   const float* __restrict__ tb,
                                                   float* __restrict__ cost) {
    int m = blockIdx.x;
    int x = m & 7;                 // XCD
    int q = m >> 3;                // 0..4095
    int b = x + 8 * (q >> 10);     // batch with b%8 == x
    int inner = q & 1023;          // 1024 blocks per batch
    int ofs = inner * 256 + (int)threadIdx.x;  // 0..NT*NP-1
    int t = ofs >> 11;
    int p = ofs & (NP - 1);
    float4 o = ((const float4*)ob)[b * NP + p];
    float4 g = ((const float4*)tb)[b * NT + t];
    float a1 = (o.z - o.x) * (o.w - o.y);
    float a2 = (g.z - g.x) * (g.w - g.y);
    cost[(size_t)b * NT * NP + ofs] = box_cost(o.x, o.y, o.z, o.w, g.x, g.y, g.z, g.w, a1, a2);
}

// ---- DPP wave-wide argmin: value-only v_min DPP chain, then ballot+readlane
// for the index. First-index tie-break exact: within-lane ties resolved by the
// strict-< local tree; cross-lane ties (popcount>1, ~never) by min-column scan.
#define DPP_ROW_SHR(n) (0x110 | (n))
#define DPP_BCAST15 0x142
#define DPP_BCAST31 0x143

template <int CTRL>
__device__ __forceinline__ float vmin_step(float v) {
    int s = __builtin_amdgcn_update_dpp(0x7149F2CA /* 1e30f */, __float_as_int(v),
                                        CTRL, 0xF, 0xF, false);
    return fminf(v, __int_as_float(s));
}

__device__ __forceinline__ void wave_argmin(float& bv, int& bj) {
    float m = bv;
    m = vmin_step<DPP_ROW_SHR(1)>(m);
    m = vmin_step<DPP_ROW_SHR(2)>(m);
    m = vmin_step<DPP_ROW_SHR(4)>(m);
    m = vmin_step<DPP_ROW_SHR(8)>(m);
    m = vmin_step<DPP_BCAST15>(m);
    m = vmin_step<DPP_BCAST31>(m);
    float g = __int_as_float(__builtin_amdgcn_readlane(__float_as_int(m), 63));
    unsigned long long win = __ballot(bv == g);
    int L = __ffsll((unsigned long long)win) - 1;
    int j = __builtin_amdgcn_readlane(bj, L);
    if (__builtin_popcountll(win) > 1) {   // exact cross-lane tie-break (rare)
        unsigned long long w = win & (win - 1);
        while (w) {
            int l = __ffsll((unsigned long long)w) - 1; w &= w - 1;
            int cj = __builtin_amdgcn_readlane(bj, l);
            j = (cj < j) ? cj : j;
        }
    }
    bv = g; bj = j;
}

#define VC(s) case s: if (lane == ow0) v_r[s] = (v_r[s] + spc_r[s]) - minv; break;

// Assigned-check without LDS: bit sl0 of owner lane ow0's asg mask, via ballot.
#define ASG_CHECK(ow, sl) (__ballot((lane == (ow)) && ((asg >> (sl)) & 1u)) != 0ull)

// Row body: consumes CUR (row I's costs), prefetches row I+1 into NXT at start.
#define ROW_BODY(I, CUR, NXT)                                                          \
  {                                                                                    \
    const int i = (I);                                                                 \
    if (i + 1 < NT) {                                                                  \
        const float4* nrow = (const float4*)(costb + (size_t)(i + 1) * NP);            \
        _Pragma("unroll") for (int g = 0; g < 8; ++g) {                                \
            float4 t4 = nrow[g * 64 + lane];                                           \
            NXT[g * 4 + 0] = t4.x; NXT[g * 4 + 1] = t4.y;                              \
            NXT[g * 4 + 2] = t4.z; NXT[g * 4 + 3] = t4.w;                              \
        }                                                                              \
    }                                                                                  \
    unsigned SCm = 0, pathm = 0;                                                       \
    int sr01 = 0;                                                                      \
    /* ---- fast first pop: cur=i, minv=0, u[i]=0 -> red = cost - v exactly ---- */    \
    float bv; int bj;                                                                  \
    {                                                                                  \
        float g0v, g2v, g4v, g6v; int g0j, g2j, g4j, g6j;                              \
        _Pragma("unroll") for (int g = 0; g < 8; g += 2) {                             \
            const int sA = g * 4, sB = sA + 4;                                         \
            const int jA = (g << 8) | lane4, jB = ((g + 1) << 8) | lane4;              \
            float a0 = CUR[sA + 0] - v_r[sA + 0]; spc_r[sA + 0] = a0;                  \
            float a1 = CUR[sA + 1] - v_r[sA + 1]; spc_r[sA + 1] = a1;                  \
            float a2 = CUR[sA + 2] - v_r[sA + 2]; spc_r[sA + 2] = a2;                  \
            float a3 = CUR[sA + 3] - v_r[sA + 3]; spc_r[sA + 3] = a3;                  \
            float b0 = CUR[sB + 0] - v_r[sB + 0]; spc_r[sB + 0] = b0;                  \
            float b1 = CUR[sB + 1] - v_r[sB + 1]; spc_r[sB + 1] = b1;                  \
            float b2 = CUR[sB + 2] - v_r[sB + 2]; spc_r[sB + 2] = b2;                  \
            float b3 = CUR[sB + 3] - v_r[sB + 3]; spc_r[sB + 3] = b3;                  \
            float mA = a0; int qA = jA;                                                \
            if (a1 < mA) { mA = a1; qA = jA + 1; }                                     \
            float mC = a2; int qC = jA + 2;                                            \
            if (a3 < mC) { mC = a3; qC = jA + 3; }                                     \
            if (mC < mA) { mA = mC; qA = qC; }                                         \
            float mB = b0; int qB = jB;                                                \
            if (b1 < mB) { mB = b1; qB = jB + 1; }                                     \
            float mD = b2; int qD = jB + 2;                                            \
            if (b3 < mD) { mD = b3; qD = jB + 3; }                                     \
            if (mD < mB) { mB = mD; qB = qD; }                                         \
            if (mB < mA) { mA = mB; qA = qB; }                                         \
            if (g == 0) { g0v = mA; g0j = qA; }                                        \
            else if (g == 2) { g2v = mA; g2j = qA; }                                   \
            else if (g == 4) { g4v = mA; g4j = qA; }                                   \
            else { g6v = mA; g6j = qA; }                                               \
        }                                                                              \
        if (g2v < g0v) { g0v = g2v; g0j = g2j; }                                       \
        if (g6v < g4v) { g4v = g6v; g4j = g6j; }                                       \
        if (g4v < g0v) { g0v = g4v; g0j = g4j; }                                       \
        bv = g0v; bj = g0j;                                                            \
    }                                                                                  \
    wave_argmin(bv, bj);                                                               \
    float mv = bv; int mj = bj;                                                        \
    int ow0 = (mj >> 2) & 63;                                                          \
    int sl0 = ((mj >> 8) << 2) | (mj & 3);                                             \
    if (lane == ow0) SCm |= (1u << sl0);                                               \
    int npops = 1;                                                                     \
    bool assigned = ASG_CHECK(ow0, sl0);                                               \
    if (assigned) {                                                                    \
        int r = row4col[mj];                                                           \
        /* ---- general shortest-path continuation ---- */                             \
        for (;;) {                                                                     \
            if ((r & 63) == lane) {                                                    \
                if (r < 64) { sr01 |= 1; pm0 = mv; }                                   \
                else        { sr01 |= 2; pm1 = mv; }                                   \
            }                                                                          \
            const int cur = r;                                                         \
            float usel = (cur >= 64) ? u1 : u0;                                        \
            float ucur = __int_as_float(                                               \
                __builtin_amdgcn_readlane(__float_as_int(usel), cur & 63));            \
            const float4* rrow = (const float4*)(costb + (size_t)cur * NP);            \
            _Pragma("unroll") for (int g = 0; g < 8; ++g) {                            \
                float4 t4 = rrow[g * 64 + lane];                                       \
                cr[g * 4 + 0] = t4.x; cr[g * 4 + 1] = t4.y;                            \
                cr[g * 4 + 2] = t4.z; cr[g * 4 + 3] = t4.w;                            \
            }                                                                          \
            bv = BIGF; bj = NP;                                                        \
            _Pragma("unroll") for (int s = 0; s < 32; ++s) {                           \
                float red = ((mv + cr[s]) - ucur) - v_r[s];                            \
                bool notSC = ((SCm >> s) & 1u) == 0u;                                  \
                bool imp = notSC && (red < spc_r[s]);                                  \
                spc_r[s] = imp ? red : spc_r[s];                                       \
                path_r[s] = imp ? cur : path_r[s];                                     \
                pathm = imp ? (pathm | (1u << s)) : pathm;                             \
                float cand = notSC ? spc_r[s] : BIGF;                                  \
                int j = (((s >> 2) << 8) | (s & 3)) | lane4;                           \
                if (cand < bv) { bv = cand; bj = j; }                                  \
            }                                                                          \
            wave_argmin(bv, bj);                                                       \
            mv = bv; mj = bj;                                                          \
            ow0 = (mj >> 2) & 63; sl0 = ((mj >> 8) << 2) | (mj & 3);                   \
            if (lane == ow0) SCm |= (1u << sl0);                                       \
            ++npops;                                                                   \
            assigned = ASG_CHECK(ow0, sl0);                                            \
            if (!assigned) break;                                                      \
            r = row4col[mj];                                                           \
        }                                                                              \
    }                                                                                  \
    const int sink = mj;                                                               \
    const float minv = mv;                                                             \
    /* ---- dual updates (exact reference order) ---- */                               \
    if ((i & 63) == lane) { if (i < 64) u0 = u0 + minv; else u1 = u1 + minv; }         \
    if (sr01 & 1) u0 = (u0 + minv) - pm0;                                              \
    if (sr01 & 2) u1 = (u1 + minv) - pm1;                                              \
    /* sink becomes assigned: update register mask (mirrors row4col[sink]>=0) */       \
    if (lane == ow0) asg |= (1u << sl0);                                               \
    if (npops == 1) {                                                                  \
        /* SC = {sink}: single-slot v-update, uniform scalar switch */                 \
        switch (sl0) {                                                                 \
            VC(0) VC(1) VC(2) VC(3) VC(4) VC(5) VC(6) VC(7)                            \
            VC(8) VC(9) VC(10) VC(11) VC(12) VC(13) VC(14) VC(15)                      \
            VC(16) VC(17) VC(18) VC(19) VC(20) VC(21) VC(22) VC(23)                    \
            VC(24) VC(25) VC(26) VC(27) VC(28) VC(29) VC(30) VC(31)                    \
        }                                                                              \
        if (lane == 0) { row4col[sink] = i; col4row[i] = sink; }                       \
    } else {                                                                           \
        _Pragma("unroll") for (int s = 0; s < 32; ++s) {                               \
            if ((SCm >> s) & 1u) v_r[s] = (v_r[s] + spc_r[s]) - minv;                  \
        }                                                                              \
        int j = sink;                                                                  \
        while (true) {                                                                 \
            int sl = ((j >> 8) << 2) | (j & 3);                                        \
            int ow = (j >> 2) & 63;                                                    \
            int pv = ((pathm >> 0) & 1u) ? path_r[0] : i;                              \
            _Pragma("unroll") for (int s = 1; s < 32; ++s) {                           \
                int leaf = ((pathm >> s) & 1u) ? path_r[s] : i;                        \
                pv = (sl == s) ? leaf : pv;                                            \
            }                                                                          \
            int ii = __builtin_amdgcn_readlane(pv, ow);                                \
            if (lane == 0) row4col[j] = ii;                                            \
            int nj = col4row[ii];                                                      \
            if (lane == 0) col4row[ii] = j;                                            \
            if (ii == i) break;                                                        \
            j = nj;                                                                    \
        }                                                                              \
    }                                                                                  \
  }

// Phase 2: wave-synchronous JV LSAP. One 64-lane wave per batch.
// Column j: owner lane = (j>>2)&63, slot = ((j>>8)<<2)|(j&3).
__global__ __launch_bounds__(64) void solve_wave(const float* __restrict__ cost,
                                                 int* __restrict__ out) {
    __shared__ int row4col[NP];
    __shared__ int col4row[NT];

    const int lane = threadIdx.x;
    const int lane4 = lane << 2;
    const int b = blockIdx.x;
    const float* costb = cost + (size_t)b * NT * NP;

    float pfA[32], pfB[32], v_r[32], spc_r[32], cr[32];
    int path_r[32];
    unsigned asg = 0;   // per-lane assigned-column bitmask (slot s of this lane)
    float u0 = 0.0f, u1 = 0.0f, pm0 = 0.0f, pm1 = 0.0f;

#pragma unroll
    for (int s = 0; s < 32; ++s) { v_r[s] = 0.0f; path_r[s] = 0; }
    for (int j = lane; j < NP; j += 64) row4col[j] = -1;
    col4row[lane] = -1;
    col4row[lane + 64] = -1;

    {   // prefetch row 0 into pfA
        const float4* r0 = (const float4*)costb;
#pragma unroll
        for (int g = 0; g < 8; ++g) {
            float4 t4 = r0[g * 64 + lane];
            pfA[g * 4 + 0] = t4.x; pfA[g * 4 + 1] = t4.y;
            pfA[g * 4 + 2] = t4.z; pfA[g * 4 + 3] = t4.w;
        }
    }

    for (int ih = 0; ih < NT / 2; ++ih) {
        ROW_BODY(2 * ih, pfA, pfB)
        ROW_BODY(2 * ih + 1, pfB, pfA)
    }

    // output: sort targets by assigned pred index (all distinct)
    for (int t = lane; t < NT; t += 64) {
        int c = col4row[t];
        int rank = 0;
        for (int t2 = 0; t2 < NT; ++t2) rank += (col4row[t2] < c) ? 1 : 0;
        out[(b * 2 + 0) * NT + rank] = c;
        out[(b * 2 + 1) * NT + rank] = t;
    }
}

// Fallback (ws too small): LDS-based block solver computing costs on the fly.
__global__ __launch_bounds__(512) void solve_fallback(const float* __restrict__ ob,
                                                      const float* __restrict__ tb,
                                                      int* __restrict__ out) {
    __shared__ float v[NP], spc[NP];
    __shared__ int path[NP], row4col[NP];
    __shared__ unsigned char SC[NP];
    __shared__ float u[NT];
    __shared__ int col4row[NT];
    __shared__ unsigned char SR[NT];
    __shared__ float rv[8];
    __shared__ int ri[8];
    __shared__ int s_cur, s_sink;
    __shared__ float s_minv;
    __shared__ float px0[NP], py0[NP], px1[NP], py1[NP], pa[NP];
    __shared__ float tx0[NT], ty0[NT], tx1[NT], ty1[NT], ta[NT];

    const int tid = threadIdx.x;
    const int b = blockIdx.x;

    for (int j = tid; j < NP; j += 512) {
        v[j] = 0.0f; row4col[j] = -1;
        float4 o = ((const float4*)ob)[b * NP + j];
        px0[j] = o.x; py0[j] = o.y; px1[j] = o.z; py1[j] = o.w;
        pa[j] = (o.z - o.x) * (o.w - o.y);
    }
    for (int t = tid; t < NT; t += 512) {
        u[t] = 0.0f; col4row[t] = -1;
        float4 g = ((const float4*)tb)[b * NT + t];
        tx0[t] = g.x; ty0[t] = g.y; tx1[t] = g.z; ty1[t] = g.w;
        ta[t] = (g.z - g.x) * (g.w - g.y);
    }
    __syncthreads();

    for (int i = 0; i < NT; ++i) {
        for (int j = tid; j < NP; j += 512) { spc[j] = BIGF; SC[j] = 0; }
        for (int t = tid; t < NT; t += 512) SR[t] = 0;
        if (tid == 0) { s_cur = i; s_minv = 0.0f; s_sink = -1; }
        __syncthreads();

        while (s_sink < 0) {
            const int cur = s_cur;
            const float minv = s_minv;
            if (tid == 0) SR[cur] = 1;
            const float ucur = u[cur];
            float c0 = tx0[cur], c1 = ty0[cur], c2 = tx1[cur], c3 = ty1[cur], ca = ta[cur];
            float bv = BIGF;
            int bi = NP;
            for (int k = 0; k < NP / 512; ++k) {
                int j = tid + k * 512;
                float cj = box_cost(px0[j], py0[j], px1[j], py1[j], c0, c1, c2, c3, pa[j], ca);
                float cand;
                if (!SC[j]) {
                    float red = ((minv + cj) - ucur) - v[j];
                    if (red < spc[j]) { spc[j] = red; path[j] = cur; }
                    cand = spc[j];
                } else {
                    cand = BIGF;
                }
                if (cand < bv || (cand == bv && j < bi)) { bv = cand; bi = j; }
            }
            for (int off = 32; off >= 1; off >>= 1) {
                float ov = __shfl_xor(bv, off);
                int oi = __shfl_xor(bi, off);
                if (ov < bv || (ov == bv && oi < bi)) { bv = ov; bi = oi; }
            }
            if ((tid & 63) == 0) { rv[tid >> 6] = bv; ri[tid >> 6] = bi; }
            __syncthreads();
            if (tid == 0) {
                float mvv = rv[0]; int mjj = ri[0];
                for (int w = 1; w < 8; ++w)
                    if (rv[w] < mvv || (rv[w] == mvv && ri[w] < mjj)) { mvv = rv[w]; mjj = ri[w]; }
                s_minv = mvv;
                SC[mjj] = 1;
                int rr = row4col[mjj];
                if (rr < 0) s_sink = mjj; else s_cur = rr;
            }
            __syncthreads();
        }

        const float minv = s_minv;
        const int sink = s_sink;
        for (int j = tid; j < NP; j += 512) if (SC[j]) v[j] = (v[j] + spc[j]) - minv;
        for (int t = tid; t < NT; t += 512) {
            if (t == i) u[t] = u[t] + minv;
            else if (SR[t]) u[t] = (u[t] + minv) - spc[col4row[t]];
        }
        __syncthreads();
        if (tid == 0) {
            int j = sink;
            while (true) {
                int ii = path[j];
                row4col[j] = ii;
                int nj = col4row[ii];
                col4row[ii] = j;
                if (ii == i) break;
                j = nj;
            }
        }
        __syncthreads();
    }

    if (tid < NT) {
        int c = col4row[tid];
        int rank = 0;
        for (int t2 = 0; t2 < NT; ++t2) rank += (col4row[t2] < c) ? 1 : 0;
        out[(b * 2 + 0) * NT + rank] = c;
        out[(b * 2 + 1) * NT + rank] = tid;
    }
}

extern "C" void kernel_launch(void* const* d_in, const int* in_sizes, int n_in,
                              void* d_out, int out_size, void* d_ws, size_t ws_size,
                              hipStream_t stream) {
    const float* ob = (const float*)d_in[0];   // [32, 2048, 4] f32
    const float* tb = (const float*)d_in[1];   // [32, 128, 4] f32
    int* out = (int*)d_out;                    // [32, 2, 128] int32

    const size_t need = (size_t)NB * NT * NP * sizeof(float);  // 32 MB
    if (ws_size >= need) {
        float* cost = (float*)d_ws;
        cost_kernel<<<(NB * NT * NP) / 256, 256, 0, stream>>>(ob, tb, cost);
        solve_wave<<<NB, 64, 0, stream>>>(cost, out);
    } else {
        solve_fallback<<<NB, 512, 0, stream>>>(ob, tb, out);
    }
}